// Round 8
// baseline (152.736 us; speedup 1.0000x reference)
//
#include <hip/hip_runtime.h>

#define MAXP    100
#define ECAP    1024           // per-event candidate cap (pow2)
#define KTARGET 3072
#define BINS    256
#define EMAX    8
#define SORTCAP 1024
#define CUTCAP  1024
#define CHK     128            // points per summation chunk
#define MAXCHUNKS 4096
#define ZWORDS  4416           // words of d_ws to zero each call
#define R2F     ((float)(0.8*0.8))   // match XLA: double product -> f32
#define MINBETA 0.1f
#define FDIM    64

__device__ __forceinline__ float dist2f(float ax, float ay, float bx, float by) {
    float dx = __fsub_rn(ax, bx);
    float dy = __fsub_rn(ay, by);
    return __fadd_rn(__fmul_rn(dx, dx), __fmul_rn(dy, dy)); // no FMA contraction
}

// ---- 0. zero the control region of d_ws (replaces pathological hipMemsetAsync) ----
__global__ void k_zero_ws(unsigned int* __restrict__ W) {
    int i = blockIdx.x * 256 + threadIdx.x;
    if (i < ZWORDS) W[i] = 0u;
}

// ---- 1. per-(event,bin) histogram of active betas ----
__global__ void k_hist(const float* __restrict__ beta, const int* __restrict__ rs,
                       int N, int E, unsigned int* __restrict__ hist) {
    __shared__ unsigned int lh[EMAX * BINS];
    __shared__ int shrs[EMAX + 1];
    int t = threadIdx.x;
    for (int i = t; i < EMAX * BINS; i += 256) lh[i] = 0;
    if (t <= E) shrs[t] = rs[t];
    __syncthreads();
    for (int p = blockIdx.x * 256 + t; p < N; p += gridDim.x * 256) {
        float b = beta[p];
        if (b >= MINBETA) {
            int bin = (int)(b * 256.0f); if (bin > 255) bin = 255;
            int e = 0;
            for (int k = 1; k <= E; ++k) e += (shrs[k] <= p) ? 1 : 0;
            atomicAdd(&lh[e * BINS + bin], 1u);
        }
    }
    __syncthreads();
    for (int i = t; i < E * BINS; i += 256) if (lh[i]) atomicAdd(&hist[i], lh[i]);
}

// ---- 2. threshold with per-event overflow guard + per-(event,bin) bases ----
__global__ __launch_bounds__(256) void k_thresh(const unsigned int* __restrict__ hist, int E,
    int* __restrict__ threshBin, unsigned int* __restrict__ evCount,
    unsigned int* __restrict__ binBase)
{
    __shared__ unsigned int h[EMAX * BINS];
    __shared__ unsigned int evacc[EMAX];
    __shared__ int sh_tb;
    int t = threadIdx.x;
    for (int i = t; i < E * BINS; i += 256) h[i] = hist[i];
    if (t < EMAX) evacc[t] = 0;
    __syncthreads();
    if (t == 0) {
        int b = BINS;
        unsigned int total = 0;
        while (b > 0 && total < KTARGET) {
            unsigned int mx = 0;
            for (int e = 0; e < E; ++e) {
                unsigned int ne = evacc[e] + h[e * BINS + b - 1];
                if (ne > mx) mx = ne;
            }
            if (mx > ECAP) break;            // next bin would overflow an event
            b--;
            for (int e = 0; e < E; ++e) { evacc[e] += h[e * BINS + b]; }
            total = 0;
            for (int e = 0; e < E; ++e) total += evacc[e];
        }
        sh_tb = b;
        *threshBin = b;
    }
    __syncthreads();
    int tb = sh_tb;
    if (t < E) evCount[t] = evacc[t];
    for (int e = 0; e < E; ++e) {
        unsigned int a = 0;
        if (t >= tb) for (int b2 = t + 1; b2 < BINS; ++b2) a += h[e * BINS + b2];
        binBase[e * BINS + t] = (t >= tb) ? ((unsigned int)(e * ECAP) + a) : 0u;
    }
}

// ---- 3. scatter candidate keys into per-(event,bin) segments ----
__global__ void k_compact(const float* __restrict__ beta, const int* __restrict__ rs,
                          int N, int E, const int* __restrict__ threshBin,
                          const unsigned int* __restrict__ binBase,
                          unsigned int* __restrict__ binCount,
                          unsigned long long* __restrict__ ukey) {
    __shared__ int shrs[EMAX + 1];
    int t = threadIdx.x;
    if (t <= E) shrs[t] = rs[t];
    __syncthreads();
    int tb = *threshBin;
    float tbf = (float)tb * (1.0f / 256.0f);   // exact pow2 scale
    for (int p = blockIdx.x * 256 + t; p < N; p += gridDim.x * 256) {
        float b = beta[p];
        if (b >= MINBETA && b >= tbf) {
            int bin = (int)(b * 256.0f); if (bin > 255) bin = 255;
            int e = 0;
            for (int k = 1; k <= E; ++k) e += (shrs[k] <= p) ? 1 : 0;
            unsigned int pos = binBase[e * BINS + bin] + atomicAdd(&binCount[e * BINS + bin], 1u);
            if (pos < (unsigned int)((e + 1) * ECAP))
                ukey[pos] = ((unsigned long long)__float_as_uint(b) << 32)
                          | (unsigned long long)(unsigned int)(~(unsigned int)p);
        }
    }
}

// ---- 4. per-(event,bin) bitonic sort (descending) ----
__global__ __launch_bounds__(1024) void k_sort(const unsigned int* __restrict__ hist,
    const int* __restrict__ threshBin, const unsigned int* __restrict__ binBase,
    unsigned long long* __restrict__ ukey)
{
    __shared__ unsigned long long sk[SORTCAP];
    int eb = blockIdx.x;
    int bin = eb & (BINS - 1);
    int tb = *threshBin;
    if (bin < tb) return;
    int cnt = (int)hist[eb];
    if (cnt <= 1) return;
    if (cnt > SORTCAP) cnt = SORTCAP;
    unsigned int base = binBase[eb];
    int t = threadIdx.x;
    int P = 1; while (P < cnt) P <<= 1;
    for (int i = t; i < P; i += 1024) sk[i] = (i < cnt) ? ukey[base + i] : 0ull;
    __syncthreads();
    for (int k = 2; k <= P; k <<= 1) {
        for (int jj = k >> 1; jj > 0; jj >>= 1) {
            for (int i = t; i < P; i += 1024) {
                int l = i ^ jj;
                if (l > i) {
                    bool up = ((i & k) == 0);
                    unsigned long long a = sk[i], c2 = sk[l];
                    bool sw = up ? (a < c2) : (a > c2);
                    if (sw) { sk[i] = c2; sk[l] = a; }
                }
            }
            __syncthreads();
        }
    }
    for (int i = t; i < cnt; i += 1024) ukey[base + i] = sk[i];
}

// ---- 5. per-event greedy: ONE WAVE per event, sorted candidates ----
__global__ __launch_bounds__(64) void k_pick(
    const float* __restrict__ cc, int E,
    const unsigned long long* __restrict__ ukey, const unsigned int* __restrict__ evCount,
    unsigned long long* __restrict__ evKey, int* __restrict__ evNp)
{
    __shared__ float pX[MAXP], pY[MAXP];
    int e = blockIdx.x;
    int ln = threadIdx.x;
    int M = (int)evCount[e]; if (M > ECAP) M = ECAP;
    const unsigned long long* cand = ukey + (size_t)e * ECAP;
    int np = 0;
    for (int base = 0; base < M && np < MAXP; base += 64) {
        int c = base + ln;
        bool valid = c < M;
        unsigned long long k = valid ? cand[c] : 0ull;
        int id = (int)(~(unsigned int)k);
        float x = 0.f, y = 0.f;
        if (valid) { float2 xy = ((const float2*)cc)[id]; x = xy.x; y = xy.y; }
        __syncthreads();                    // order prev batch's pX/pY writes (1 wave, cheap)
        // parallel pre-filter vs all existing picks (uniform trip count, no break)
        bool cov = !valid;
        for (int q = 0; q < np; ++q)
            cov = cov | (dist2f(x, y, pX[q], pY[q]) <= R2F);
        // resolve batch in sorted order: one step per NEW pick
        while (np < MAXP) {
            unsigned long long uncov = __ballot(!cov);
            if (uncov == 0ull) break;
            int j = __ffsll((long long)uncov) - 1;
            float jx = __shfl(x, j, 64);
            float jy = __shfl(y, j, 64);
            if (ln == j) {
                pX[np] = x; pY[np] = y;
                evKey[(size_t)e * 128 + np] = k;
            }
            np++;
            if (!cov) cov = (dist2f(x, y, jx, jy) <= R2F);   // lane j covers itself (d=0)
        }
    }
    if (ln == 0) evNp[e] = np;
}

// ---- 6. global cut to top-100 pick keys + grouped output ----
__global__ __launch_bounds__(256) void k_cut(const float* __restrict__ cc, int E,
    const unsigned long long* __restrict__ evKey, const int* __restrict__ evNp,
    float* __restrict__ gX, float* __restrict__ gY, int* __restrict__ gId,
    int* __restrict__ segStart, int* __restrict__ npickOut)
{
    __shared__ unsigned long long sk[CUTCAP];
    __shared__ int kept[EMAX], segS[EMAX + 1];
    int t = threadIdx.x;
    int P = 1; while (P < E * 128) P <<= 1;   // 512 for E=4
    for (int i = t; i < P; i += 256) sk[i] = 0ull;
    if (t < EMAX) kept[t] = 0;
    __syncthreads();
    for (int e = 0; e < E; ++e) {
        int n = evNp[e];
        if (t < n) sk[e * 128 + t] = evKey[e * 128 + t];
    }
    __syncthreads();
    for (int kk = 2; kk <= P; kk <<= 1) {
        for (int jj = kk >> 1; jj > 0; jj >>= 1) {
            for (int i = t; i < P; i += 256) {
                int l = i ^ jj;
                if (l > i) {
                    bool up = ((i & kk) == 0);
                    unsigned long long a = sk[i], b = sk[l];
                    bool sw = up ? (a < b) : (a > b);
                    if (sw) { sk[i] = b; sk[l] = a; }
                }
            }
            __syncthreads();
        }
    }
    unsigned long long thr = sk[MAXP - 1];
    __syncthreads();
    for (int e = 0; e < E; ++e) {
        int n = evNp[e];
        if (t < n) {
            unsigned long long kv = evKey[e * 128 + t];
            if (kv >= thr && kv != 0ull) atomicAdd(&kept[e], 1);
        }
    }
    __syncthreads();
    if (t == 0) {
        int acc = 0;
        for (int e = 0; e < E; ++e) { segS[e] = acc; acc += kept[e]; }
        segS[E] = acc;
        *npickOut = acc;
        for (int e = 0; e <= E; ++e) segStart[e] = segS[e];
    }
    __syncthreads();
    for (int e = 0; e < E; ++e) {
        int kc = kept[e];                       // kept picks are a key-descending prefix
        if (t < kc) {
            unsigned long long kv = evKey[e * 128 + t];
            int dst = segS[e] + t;
            int id = (int)(~(unsigned int)kv);
            gId[dst] = id;
            float2 xy = ((const float2*)cc)[id];
            gX[dst] = xy.x; gY[dst] = xy.y;
        }
    }
}

// ---- 7. asso + zero-fill summed + per-pick histogram (fused) ----
__global__ __launch_bounds__(256) void k_asso(const float* __restrict__ cc,
                       const int* __restrict__ rs, int N, int E,
                       const float* __restrict__ gX, const float* __restrict__ gY,
                       const int* __restrict__ gId, const int* __restrict__ segStart,
                       float* __restrict__ assoOut, int* __restrict__ assoJ,
                       float* __restrict__ outSummed, unsigned int* __restrict__ cntJ)
{
    __shared__ float sx[MAXP], sy[MAXP];
    __shared__ int   sid[MAXP];
    __shared__ int   sstart[EMAX + 1], shrs[EMAX + 1];
    __shared__ unsigned int lcnt[MAXP];
    int t = threadIdx.x;
    if (t <= E) { sstart[t] = segStart[t]; shrs[t] = rs[t]; }
    for (int i = t; i < MAXP; i += 256) lcnt[i] = 0;
    __syncthreads();
    int np = sstart[E];
    if (t < np) { sx[t] = gX[t]; sy[t] = gY[t]; sid[t] = gId[t]; }
    __syncthreads();
    // zero this block's 256 summed rows (256*64 floats = 4096 float4)
    {
        size_t base4 = (size_t)blockIdx.x * 4096;
        size_t lim4 = ((size_t)N * FDIM) >> 2;
        float4 z = make_float4(0.f, 0.f, 0.f, 0.f);
        float4* o4 = (float4*)outSummed;
        for (int i = t; i < 4096; i += 256) {
            size_t idx = base4 + i;
            if (idx < lim4) o4[idx] = z;
        }
    }
    int p = blockIdx.x * 256 + t;
    int j = -1;
    if (p < N) {
        float2 xy = ((const float2*)cc)[p];
        int e = 0;
        for (int k = 1; k <= E; ++k) e += (shrs[k] <= p) ? 1 : 0;
        int q1 = sstart[e + 1];
        for (int q = sstart[e]; q < q1; ++q) {
            if (dist2f(xy.x, xy.y, sx[q], sy[q]) <= R2F) { j = q; break; }
        }
        assoJ[p] = j;
        assoOut[p] = (j >= 0) ? (float)sid[j] : -1.0f;
        if (j >= 0) atomicAdd(&lcnt[j], 1u);
    }
    __syncthreads();
    if (t < np && lcnt[t]) atomicAdd(&cntJ[t], lcnt[t]);
}

// ---- 8. offsets + chunk table (tiny, one block) ----
__global__ __launch_bounds__(256) void k_chunks(const int* __restrict__ npick,
    const unsigned int* __restrict__ cntJ, int* __restrict__ offs,
    int* __restrict__ chunkJ, int* __restrict__ chunkStart, int* __restrict__ chunkLen,
    int* __restrict__ nchunks)
{
    __shared__ int scnt[MAXP], soff[MAXP + 1], sbase[MAXP + 1];
    int t = threadIdx.x;
    int np = *npick;
    if (t < np) scnt[t] = (int)cntJ[t];
    __syncthreads();
    if (t == 0) {
        int acc = 0, cb = 0;
        for (int j = 0; j < np; ++j) {
            soff[j] = acc; sbase[j] = cb;
            acc += scnt[j];
            cb += (scnt[j] + CHK - 1) / CHK;
        }
        soff[np] = acc;
        *nchunks = cb > MAXCHUNKS ? MAXCHUNKS : cb;
    }
    __syncthreads();
    if (t <= np) offs[t] = soff[t];
    if (t < np) {
        int nc = (scnt[t] + CHK - 1) / CHK;
        for (int k = 0; k < nc; ++k) {
            int ci = sbase[t] + k;
            if (ci < MAXCHUNKS) {
                chunkJ[ci] = t;
                chunkStart[ci] = soff[t] + k * CHK;
                int rem = scnt[t] - k * CHK;
                chunkLen[ci] = rem < CHK ? rem : CHK;
            }
        }
    }
}

// ---- 9. scatter point ids grouped by pick (LDS-staged ranks) ----
#define SPT 4
__global__ __launch_bounds__(256) void k_scatter(const int* __restrict__ assoJ, int N,
    const int* __restrict__ offs, unsigned int* __restrict__ cursor,
    int* __restrict__ sortedIdx)
{
    __shared__ unsigned int lcnt[MAXP];
    __shared__ unsigned int lbase[MAXP];
    __shared__ int loff[MAXP];
    int t = threadIdx.x;
    for (int i = t; i < MAXP; i += 256) lcnt[i] = 0;
    __syncthreads();
    int bs = blockIdx.x * (256 * SPT);
    int lj[SPT]; unsigned int lpos[SPT];
#pragma unroll
    for (int s = 0; s < SPT; ++s) {
        int p = bs + s * 256 + t;
        int j = (p < N) ? assoJ[p] : -1;
        lj[s] = j;
        lpos[s] = (j >= 0) ? atomicAdd(&lcnt[j], 1u) : 0u;
    }
    __syncthreads();
    for (int i = t; i < MAXP; i += 256) {
        unsigned int c = lcnt[i];
        lbase[i] = c ? atomicAdd(&cursor[i], c) : 0u;
        loff[i] = offs[i];
    }
    __syncthreads();
#pragma unroll
    for (int s = 0; s < SPT; ++s) {
        int j = lj[s];
        if (j >= 0) {
            int p = bs + s * 256 + t;
            sortedIdx[loff[j] + (int)(lbase[j] + lpos[s])] = p;
        }
    }
}

// ---- 10. per-chunk register-accumulated sum (grid-stride, deep prefetch) ----
__global__ __launch_bounds__(256) void k_sum(const float* __restrict__ feat,
    const int* __restrict__ sortedIdx,
    const int* __restrict__ chunkJ, const int* __restrict__ chunkStart,
    const int* __restrict__ chunkLen, const int* __restrict__ nchunks,
    const int* __restrict__ gId, float* __restrict__ outSummed)
{
    __shared__ float red[16][65];
    int nc = *nchunks;
    int t = threadIdx.x;
    int sub = t >> 4, q = t & 15;
    const float4* feat4 = (const float4*)feat;
    for (int b = blockIdx.x; b < nc; b += gridDim.x) {
        int j = chunkJ[b], cs = chunkStart[b], len = chunkLen[b];
        float4 acc = make_float4(0.f, 0.f, 0.f, 0.f);
        // pipeline: idx 2 ahead, feat 1 ahead
        int i = sub;
        int pA = (i < len) ? sortedIdx[cs + i] : -1;
        int pB = (i + 16 < len) ? sortedIdx[cs + i + 16] : -1;
        float4 f = (pA >= 0) ? feat4[(size_t)pA * 16 + q] : make_float4(0.f,0.f,0.f,0.f);
        for (; i < len; i += 16) {
            int pC = (i + 32 < len) ? sortedIdx[cs + i + 32] : -1;
            float4 fN = (pB >= 0) ? feat4[(size_t)pB * 16 + q] : make_float4(0.f,0.f,0.f,0.f);
            acc.x += f.x; acc.y += f.y; acc.z += f.z; acc.w += f.w;
            f = fN; pB = pC;
        }
        red[sub][q * 4 + 0] = acc.x;
        red[sub][q * 4 + 1] = acc.y;
        red[sub][q * 4 + 2] = acc.z;
        red[sub][q * 4 + 3] = acc.w;
        __syncthreads();
        if (t < FDIM) {
            float s = 0.f;
#pragma unroll
            for (int ss = 0; ss < 16; ++ss) s += red[ss][t];
            atomicAdd(&outSummed[(size_t)gId[j] * FDIM + t], s);
        }
        __syncthreads();
    }
}

extern "C" void kernel_launch(void* const* d_in, const int* in_sizes, int n_in,
                              void* d_out, int out_size, void* d_ws, size_t ws_size,
                              hipStream_t stream)
{
    const float* cc   = (const float*)d_in[0];
    const float* beta = (const float*)d_in[1];
    const float* feat = (const float*)d_in[2];
    const int*   rs   = (const int*)d_in[3];
    int N = in_sizes[1];
    int E = in_sizes[3] - 1;
    float* outSummed = (float*)d_out;
    float* outAsso   = (float*)d_out + (size_t)N * FDIM;

    // workspace layout (32-bit word offsets)
    unsigned int* W = (unsigned int*)d_ws;
    unsigned int* hist      = W + 0;                 // 2048
    unsigned int* binCount  = W + 2048;              // 2048
    unsigned int* cntJ      = W + 4096;              // 128
    unsigned int* cursor    = W + 4224;              // 128
    int*          threshBin = (int*)(W + 4352);
    int*          npick     = (int*)(W + 4353);
    int*          nchunks   = (int*)(W + 4354);
    int*          segStartW = (int*)(W + 4356);      // 9
    int*          evNp      = (int*)(W + 4368);      // 8
    unsigned int* evCount   = W + 4376;              // 8
    // ---- end of zeroed region (ZWORDS=4416 words) ----
    unsigned int* binBase   = W + 4416;              // 2048
    unsigned long long* ukey = (unsigned long long*)(W + 6464);   // EMAX*ECAP u64 = 16384 w
    unsigned long long* evKey = (unsigned long long*)(W + 22848); // EMAX*128 u64 = 2048 w
    float* gX   = (float*)(W + 24896);               // 128
    float* gY   = (float*)(W + 25024);               // 128
    int*   gId  = (int*)(W + 25152);                 // 128
    int*   offs = (int*)(W + 25280);                 // 128+pad
    int*   chunkJ     = (int*)(W + 25600);           // 4096
    int*   chunkStart = (int*)(W + 29696);           // 4096
    int*   chunkLen   = (int*)(W + 33792);           // 4096
    int*   assoJ      = (int*)(W + 37888);           // N
    int*   sortedIdx  = assoJ + N;                   // N

    int gblocks = (N + 255) / 256; if (gblocks > 1024) gblocks = 1024;
    int ablocks = (N + 255) / 256;
    int sblocks = (N + 256 * SPT - 1) / (256 * SPT);
    k_zero_ws<<<(ZWORDS + 255) / 256, 256, 0, stream>>>(W);
    k_hist   <<<gblocks, 256, 0, stream>>>(beta, rs, N, E, hist);
    k_thresh <<<1, 256, 0, stream>>>(hist, E, threshBin, evCount, binBase);
    k_compact<<<gblocks, 256, 0, stream>>>(beta, rs, N, E, threshBin, binBase, binCount, ukey);
    k_sort   <<<E * BINS, 1024, 0, stream>>>(hist, threshBin, binBase, ukey);
    k_pick   <<<E, 64, 0, stream>>>(cc, E, ukey, evCount, evKey, evNp);
    k_cut    <<<1, 256, 0, stream>>>(cc, E, evKey, evNp, gX, gY, gId, segStartW, npick);
    k_asso   <<<ablocks, 256, 0, stream>>>(cc, rs, N, E, gX, gY, gId, segStartW, outAsso, assoJ, outSummed, cntJ);
    k_chunks <<<1, 256, 0, stream>>>(npick, cntJ, offs, chunkJ, chunkStart, chunkLen, nchunks);
    k_scatter<<<sblocks, 256, 0, stream>>>(assoJ, N, offs, cursor, sortedIdx);
    k_sum    <<<1024, 256, 0, stream>>>(feat, sortedIdx, chunkJ, chunkStart, chunkLen, nchunks, gId, outSummed);
}